// Round 10
// baseline (1060.372 us; speedup 1.0000x reference)
//
// LSTM model fused pipeline for MI355X (gfx950).
// Pipeline: prep(bf16 converts) -> fused {xproj + recurrence + h1} streaming kernel -> out GEMM.
// R10: allocator-proof restructure. R0-R9 forensics: every config spilled/rematerialized
//   (1024-thr: VGPR=64, WRITE_SIZE 14.4MB scratch; 512-thr: VGPR 124-128 vs live ~190 ->
//   per-step L2 remat) because the allocator is LDS-blind and targets 8 waves/EU. ~40-60
//   serialized ~250cy reloads/step = ~6us/step = the invariant 236us.
//   Fix: NO persistent weight registers. 512 thr / 8 waves / 7 tiles each; A-frags (Wh',Wx')
//   stream from L2 every step via a 1-ahead 2-slot ring (17 kb: 7 h + 10 x). Peak live ~115
//   < the 124-128 that 512-thr builds reliably get. Weights are identical across WGs -> L2
//   resident (975KB). Math identical to R8 (which PASSED, absmax 1.5e-5). No xp, no k_xproj.
#include <hip/hip_runtime.h>
#include <stdint.h>

#define TT_  40
#define V_   50257
#define VP_  50432    // padded vocab rows (197*256)

typedef __attribute__((ext_vector_type(4))) float f32x4;
typedef __attribute__((ext_vector_type(8))) short s16x8;

__device__ __forceinline__ ushort bfrn(float f) {
  union { float f; uint32_t u; } x; x.f = f;
  return (ushort)((x.u + 0x7fffu + ((x.u >> 16) & 1u)) >> 16);
}
__device__ __forceinline__ float sigm(float x) { return 1.f / (1.f + __expf(-x)); }
__device__ __forceinline__ float tanh_f(float x) { return 1.f - 2.f / (__expf(2.f*x) + 1.f); }

template<int N> struct IC { static constexpr int v = N; };

// ---------------- prep: emb -> bf16 [VP_][320] (rows>=V_ and k>=300 zeroed) ----------------
__global__ void k_prep_emb(const float* __restrict__ emb, ushort* __restrict__ emb_bf) {
  const int idx = blockIdx.x * 256 + threadIdx.x;       // VP_*80 exact
  const int v = idx / 80, kc = idx % 80;
  ushort4 o = {0, 0, 0, 0};
  if (v < V_ && kc < 75) {
    const float4 f = *(const float4*)(emb + (size_t)v * 300 + kc * 4);
    o.x = bfrn(f.x); o.y = bfrn(f.y); o.z = bfrn(f.z); o.w = bfrn(f.w);
  }
  *(ushort4*)(emb_bf + (size_t)v * 320 + kc * 4) = o;
}

// ---- prep: Wx -> [896][320] bf16 (col-interleaved col'=4n+g), Wh -> [896][224], U -> U_t[300][200]
__global__ void k_prep_small(const float* __restrict__ Wx, const float* __restrict__ Wh,
                             const float* __restrict__ U, ushort* __restrict__ Wxp,
                             ushort* __restrict__ Whp, float* __restrict__ Ut) {
  int idx = blockIdx.x * 256 + threadIdx.x;
  if (idx < 896 * 320) {
    const int colp = idx / 320, k = idx % 320;
    const int n = colp >> 2, g = colp & 3;
    const float v = (colp < 800 && k < 300) ? Wx[(size_t)k * 800 + g * 200 + n] : 0.f;
    Wxp[idx] = bfrn(v);
    return;
  }
  idx -= 896 * 320;
  if (idx < 896 * 224) {
    const int colp = idx / 224, k = idx % 224;
    const int n = colp >> 2, g = colp & 3;
    const float v = (colp < 800 && k < 200) ? Wh[(size_t)k * 800 + g * 200 + n] : 0.f;
    Whp[idx] = bfrn(v);
    return;
  }
  idx -= 896 * 224;
  if (idx < 300 * 200) {
    const int d = idx / 200, h = idx % 200;
    Ut[idx] = U[(size_t)h * 300 + d];
  }
}

// ------- fused LSTM: 32 WGs x 16 batch rows; 512 thr / 8 waves x 7 tiles -------------------
// Per step per wave: acc[tl] += sum over 17 kb-blocks of mfma(A=W'[tile,kb], B={h|x}[kb]).
// kb 0..6: A from Whp (K=224), B=h from LDS dbuf. kb 7..16: A from Wxp (K=320), B=x gathered
// per-lane from emb_bf. 2-slot 1-ahead ring; A never cached across steps (L2-resident).
__global__ __launch_bounds__(512)
void k_lstm(
    const int* __restrict__ ids, const ushort* __restrict__ emb_bf,
    const ushort* __restrict__ Wxp, const ushort* __restrict__ Whp,
    const int* __restrict__ lengths, const float* __restrict__ bg,
    const float* __restrict__ Ut, const float* __restrict__ b1v,
    ushort* __restrict__ h1bf) {
  __shared__ ushort h_lds[2][3584];      // 2 x 7 kb x 1024B fragment-linear h (bf16, K=224)
  __shared__ float  c_lds[16 * 228];     // cell state dump (end only)
  __shared__ float  bb_lds[4 * 224];     // bias b' as [g][n]

  const int tid = threadIdx.x;
  const int w = tid >> 6, lane = tid & 63;
  const int l15 = lane & 15, q = lane >> 4;
  const int b0 = blockIdx.x << 4;
  const int len = lengths[b0 + l15];

  for (int i = tid; i < 896; i += 512) {
    const int g = i / 224, n = i % 224;
    bb_lds[i] = (n < 200) ? bg[g * 200 + n] : 0.f;
  }
  for (int i = tid; i < 3584; i += 512) ((uint32_t*)h_lds)[i] = 0;  // zero both h buffers

  // per-lane A bases (tile T0 = w*7+tl; row = T0*16+l15; k-chunk q*8)
  const ushort* whb = Whp + (size_t)(w * 7 * 16 + l15) * 224 + q * 8;   // +tl*3584 +kb*32
  const ushort* wxb = Wxp + (size_t)(w * 7 * 16 + l15) * 320 + q * 8;   // +tl*5120 +kb*32
  const int* idrow = ids + (size_t)(b0 + l15) * TT_;

  float  cr[7] = {0.f, 0.f, 0.f, 0.f, 0.f, 0.f, 0.f};   // owner-lane cell state
  ushort hr[7] = {0, 0, 0, 0, 0, 0, 0};                 // owner-lane h (freeze path)

  __syncthreads();

  auto step = [&](int t, auto BUFC) {
    constexpr int BUF = decltype(BUFC)::v;
    const int idc = idrow[t];                            // L1/L2-hot after step 0
    const ushort* xrow = emb_bf + (size_t)idc * 320 + q * 8;

    s16x8 wA[2][7];                                      // A ring (2 slots x 7 tiles)
    s16x8 bB[2];                                         // B ring
    // kb indexing: 0..6 = h-phase (Whp, K=224), 7..16 = x-phase (Wxp, K=320)
    auto LOADK = [&](int kb, int slot) {
      if (kb < 7) {
        bB[slot] = *(const s16x8*)(&h_lds[BUF][kb * 512 + lane * 8]);
#pragma unroll
        for (int tl = 0; tl < 7; ++tl)
          wA[slot][tl] = *(const s16x8*)(whb + tl * 3584 + kb * 32);
      } else {
        bB[slot] = *(const s16x8*)(xrow + (kb - 7) * 32);
#pragma unroll
        for (int tl = 0; tl < 7; ++tl)
          wA[slot][tl] = *(const s16x8*)(wxb + tl * 5120 + (kb - 7) * 32);
      }
    };

    f32x4 acc[7];
    const f32x4 z = {0.f, 0.f, 0.f, 0.f};
#pragma unroll
    for (int tl = 0; tl < 7; ++tl) acc[tl] = z;

    LOADK(0, 0);
#pragma unroll
    for (int kb = 0; kb < 17; ++kb) {
      if (kb + 1 < 17) LOADK(kb + 1, (kb + 1) & 1);      // 1-ahead into the OTHER slot
#pragma unroll
      for (int tl = 0; tl < 7; ++tl)
        acc[tl] = __builtin_amdgcn_mfma_f32_16x16x32_bf16(wA[kb & 1][tl], bB[kb & 1], acc[tl], 0, 0, 0);
    }

    // epilogue: lane (q,l15) owns unit n=(w*7+tl)*4+q, batch l15; acc[tl][r] = gate r
    const bool act = (t < len);
#pragma unroll
    for (int tl = 0; tl < 7; ++tl) {
      const int n = (w * 7 + tl) * 4 + q;
      const float g0 = acc[tl][0] + bb_lds[n];          // i
      const float g1 = acc[tl][1] + bb_lds[224 + n];    // j
      const float g2 = acc[tl][2] + bb_lds[448 + n];    // f
      const float g3 = acc[tl][3] + bb_lds[672 + n];    // o
      if (n < 200) {
        if (act) {
          const float sf = sigm(g2 + 1.f);              // forget_bias = 1
          const float si = sigm(g0);
          const float tj = tanh_f(g1);
          const float cn = sf * cr[tl] + si * tj;
          cr[tl] = cn;
          hr[tl] = bfrn(sigm(g3) * tanh_f(cn));
        }
        const int hwoff = (n >> 5) * 1024 + (l15 + (((n >> 3) & 3) << 4)) * 16 + (n & 7) * 2;
        *(ushort*)((char*)(&h_lds[BUF ^ 1][0]) + hwoff) = hr[tl];
      }
    }
    __syncthreads();   // publishes h for next step
  };

  for (int tt = 0; tt < TT_ / 2; ++tt) {
    step(2 * tt,     IC<0>{});
    step(2 * tt + 1, IC<1>{});
  }

  // dump owner-lane c into c_lds for the h1 GEMM
#pragma unroll
  for (int tl = 0; tl < 7; ++tl) {
    const int n = (w * 7 + tl) * 4 + q;
    if (n < 200) c_lds[l15 * 228 + n] = cr[tl];
  }
  __syncthreads();

  // h1 = relu(c @ U + b1) -> bf16 [16][320] (cols 300..319 zero)
  for (int i = tid; i < 4800; i += 512) {
    const int col = i >> 4, row = i & 15;
    const float* ut = Ut + col * 200;
    const float* cc_ = &c_lds[row * 228];
    float s = 0.f;
    for (int k = 0; k < 200; k += 4) {
      const float4 cv = *(const float4*)(cc_ + k);
      const float4 uu = *(const float4*)(ut + k);
      s += cv.x * uu.x + cv.y * uu.y + cv.z * uu.z + cv.w * uu.w;
    }
    s += b1v[col];
    h1bf[(size_t)(b0 + row) * 320 + col] = bfrn(fmaxf(s, 0.f));
  }
  if (tid < 320) {
    const int row = tid & 15, col = 300 + (tid >> 4);
    h1bf[(size_t)(b0 + row) * 320 + col] = 0;
  }
}

// ---------------- out = h1 @ emb^T + b2 : [512][50257] f32 ----------------
__global__ __launch_bounds__(256) void k_out(
    const ushort* __restrict__ h1bf, const ushort* __restrict__ emb_bf,
    const float* __restrict__ b2, float* __restrict__ out) {
  const int tid = threadIdx.x;
  const int w = tid >> 6, lane = tid & 63;
  const int l15 = lane & 15, q = lane >> 4;
  const int m0 = blockIdx.y << 6;
  const int n0 = blockIdx.x * 256 + w * 64;
  f32x4 acc[4][4];
  const f32x4 z = {0.f, 0.f, 0.f, 0.f};
#pragma unroll
  for (int a = 0; a < 4; ++a)
#pragma unroll
    for (int b = 0; b < 4; ++b) acc[a][b] = z;
  for (int kb = 0; kb < 10; ++kb) {
    s16x8 af[4], bfv[4];
#pragma unroll
    for (int mt = 0; mt < 4; ++mt)
      af[mt] = *(const s16x8*)(h1bf + (size_t)(m0 + mt * 16 + l15) * 320 + kb * 32 + q * 8);
#pragma unroll
    for (int nt = 0; nt < 4; ++nt)
      bfv[nt] = *(const s16x8*)(emb_bf + (size_t)(n0 + nt * 16 + l15) * 320 + kb * 32 + q * 8);
#pragma unroll
    for (int mt = 0; mt < 4; ++mt)
#pragma unroll
      for (int nt = 0; nt < 4; ++nt)
        acc[mt][nt] = __builtin_amdgcn_mfma_f32_16x16x32_bf16(af[mt], bfv[nt], acc[mt][nt], 0, 0, 0);
  }
#pragma unroll
  for (int nt = 0; nt < 4; ++nt) {
    const int col = n0 + nt * 16 + l15;
    if (col < V_) {
      const float bb = b2[col];
#pragma unroll
      for (int mt = 0; mt < 4; ++mt) {
        const int row = m0 + mt * 16 + q * 4;
#pragma unroll
        for (int r = 0; r < 4; ++r)
          out[(size_t)(row + r) * V_ + col] = acc[mt][nt][r] + bb;
      }
    }
  }
}

extern "C" void kernel_launch(void* const* d_in, const int* in_sizes, int n_in,
                              void* d_out, int out_size, void* d_ws, size_t ws_size,
                              hipStream_t stream) {
  (void)in_sizes; (void)n_in; (void)out_size; (void)ws_size;
  const int*   ids  = (const int*)d_in[0];
  const int*   lens = (const int*)d_in[1];
  const float* emb  = (const float*)d_in[2];
  const float* Wx   = (const float*)d_in[3];
  const float* Wh   = (const float*)d_in[4];
  const float* bg   = (const float*)d_in[5];
  const float* U    = (const float*)d_in[6];
  const float* b1   = (const float*)d_in[7];
  const float* b2   = (const float*)d_in[8];
  float* out = (float*)d_out;

  char* ws = (char*)d_ws;                       // ws usage ~33.8 MB
  ushort* emb_bf = (ushort*)(ws);               // VP_*320*2       = 32,276,480
  ushort* Wxp    = (ushort*)(ws + 32276480);    // 896*320*2       =    573,440
  ushort* Whp    = (ushort*)(ws + 32849920);    // 896*224*2       =    401,408
  float*  Ut     = (float*)(ws + 33251328);     // 300*200*4       =    240,000
  ushort* h1bf   = (ushort*)(ws + 33491328);    // 512*320*2       =    327,680

  k_prep_emb  <<<15760, 256, 0, stream>>>(emb, emb_bf);
  k_prep_small<<<2139,  256, 0, stream>>>(Wx, Wh, U, Wxp, Whp, Ut);
  k_lstm      <<<32, 512, 0, stream>>>(ids, emb_bf, Wxp, Whp, lens, bg, Ut, b1, h1bf);
  k_out       <<<dim3(197, 8), 256, 0, stream>>>(h1bf, emb_bf, b2, out);
}